// Round 21
// baseline (1117.513 us; speedup 1.0000x reference)
//
#include <hip/hip_runtime.h>
#include <hip/hip_bf16.h>
#include <math.h>

// ---------------------------------------------------------------------------
// GAT 2-layer network on MI355X.
// r21 = r20 CSR (src-tiled parallel-scan) + r18 h layout + TB=8 SINGLE-SWEEP
// edge kernels: per-edge esrc/bpermute/readlane overhead halved vs 2x TB=4
// sweeps; alpha tables stored bf16 t-inner-per-head (asrc[n][h][8t], 16B) so
// per-edge alpha traffic halves. Lean registers (no staged arrays) to avoid
// r19's 92-VGPR occupancy collapse. No online max. f32 accumulation.
// ---------------------------------------------------------------------------

typedef __hip_bfloat16 bf16;

#define TILES  16
#define TSHIFT 12   // tile = src >> 12  (4096 nodes/tile)

__device__ __forceinline__ float bf2f(unsigned short u) {
    return __uint_as_float(((unsigned int)u) << 16);
}
__device__ __forceinline__ float lo16(int u) {
    return __uint_as_float(((unsigned)u) << 16);
}
__device__ __forceinline__ float hi16(int u) {
    return __uint_as_float(((unsigned)u) & 0xFFFF0000u);
}
__device__ __forceinline__ unsigned short f2bfu(float f) {
    bf16 b = __float2bfloat16(f);
    return *reinterpret_cast<unsigned short*>(&b);
}

// ---- CSR construction (src-tiled, parallel scan) ---------------------------

__global__ __launch_bounds__(256) void count2_kernel(const int* __restrict__ srcs,
                                                     const int* __restrict__ dsts,
                                                     int* cnt2, int E) {
    int i = blockIdx.x * 256 + threadIdx.x;
    if (i < E) atomicAdd(&cnt2[dsts[i] * TILES + (srcs[i] >> TSHIFT)], 1);
}

__device__ __forceinline__ int bucket_val(const int* __restrict__ cnt2, int idx, int M) {
    if (idx >= M) return 0;
    int n = idx >> 4, tile = idx & (TILES - 1);
    return cnt2[idx] + ((tile == (n >> TSHIFT)) ? 1 : 0);   // self-loop folded in
}

__global__ __launch_bounds__(256) void scanA_kernel(const int* __restrict__ cnt2,
                                                    int* bsum, int M) {
    __shared__ int sd[256];
    int tid = threadIdx.x;
    int idx = blockIdx.x * 256 + tid;
    int v = bucket_val(cnt2, idx, M);
    sd[tid] = v;
    __syncthreads();
    for (int off = 128; off > 0; off >>= 1) {
        if (tid < off) sd[tid] += sd[tid + off];
        __syncthreads();
    }
    if (tid == 0) bsum[blockIdx.x] = sd[0];
}

__global__ __launch_bounds__(1024) void scanB_kernel(const int* __restrict__ bsum,
                                                     int* boff, int B) {
    __shared__ int ls[1024];
    int t = threadIdx.x;
    int chunk = (B + 1023) / 1024;
    int b = t * chunk;
    int sum = 0;
    for (int i = 0; i < chunk; ++i) {
        int idx = b + i;
        if (idx < B) sum += bsum[idx];
    }
    ls[t] = sum;
    __syncthreads();
    for (int off = 1; off < 1024; off <<= 1) {
        int v = (t >= off) ? ls[t - off] : 0;
        __syncthreads();
        ls[t] += v;
        __syncthreads();
    }
    int run = (t == 0) ? 0 : ls[t - 1];
    for (int i = 0; i < chunk; ++i) {
        int idx = b + i;
        if (idx < B) {
            boff[idx] = run;
            run += bsum[idx];
        }
    }
}

__global__ __launch_bounds__(256) void scanC_kernel(const int* __restrict__ cnt2,
                                                    const int* __restrict__ boff,
                                                    int* cur2, int* rowp, int M, int N) {
    __shared__ int sd[256];
    int tid = threadIdx.x;
    int idx = blockIdx.x * 256 + tid;
    int v = bucket_val(cnt2, idx, M);
    sd[tid] = v;
    __syncthreads();
    for (int off = 1; off < 256; off <<= 1) {
        int t = (tid >= off) ? sd[tid - off] : 0;
        __syncthreads();
        sd[tid] += t;
        __syncthreads();
    }
    int inc = sd[tid];
    int go  = boff[blockIdx.x] + inc - v;
    if (idx < M) {
        cur2[idx] = go;
        if ((idx & (TILES - 1)) == 0) rowp[idx >> 4] = go;
        if (idx == M - 1) rowp[N] = go + v;
    }
}

__global__ __launch_bounds__(256) void fill2_kernel(const int* __restrict__ srcs,
                                                    const int* __restrict__ dsts,
                                                    int* cur2, int* esrc, int E, int N) {
    int i = blockIdx.x * 256 + threadIdx.x;
    if (i >= E + N) return;
    int s, d;
    if (i < E) { s = srcs[i]; d = dsts[i]; }
    else       { s = i - E;   d = s; }      // self-loops
    int pos = atomicAdd(&cur2[d * TILES + (s >> TSHIFT)], 1);
    esrc[pos] = s;
}

// ---- vector loaders --------------------------------------------------------

__device__ __forceinline__ float4 ld4(const float* p) { return *(const float4*)p; }
__device__ __forceinline__ float4 ld4(const bf16* p) {
    ushort4 u = *(const ushort4*)p;
    float4 r;
    r.x = bf2f(u.x); r.y = bf2f(u.y); r.z = bf2f(u.z); r.w = bf2f(u.w);
    return r;
}

// ---- GEMM (h = x@W) fused with attention dot-products, t-batched rows ------
// grid (N/4, 2): wave = node n, rows = timesteps t0..t0+3.
// Outputs: h[n][8t][64c] bf16; asrc[n][H][8t] bf16; adst[n][H][8t] f32.

template <typename TIN, int H, int C>
__global__ __launch_bounds__(256) void gemm_att_kernel(
    const TIN* __restrict__ xin,
    size_t node_stride, size_t t_stride,
    const float* __restrict__ Wm,    // [64,64]
    const float* __restrict__ att_s, // [H*C]
    const float* __restrict__ att_d, // [H*C]
    bf16* __restrict__ hout,         // [N][8*64] bf16 (t-inner)
    unsigned short* __restrict__ asrc, // [N][H][8] bf16
    float* __restrict__ adst,        // [N][H][8] f32
    int N) {
    __shared__ float Ws[64 * 64];
    int tid = threadIdx.x;
    {
        const float4* W4 = (const float4*)Wm;
        float4* Ws4 = (float4*)Ws;
#pragma unroll
        for (int i = 0; i < 4; ++i) Ws4[tid + 256 * i] = W4[tid + 256 * i];
    }
    __syncthreads();

    int c  = tid & 63;
    int wv = tid >> 6;
    int t0 = blockIdx.y * 4;
    int n  = blockIdx.x * 4 + wv;
    if (n >= N) return;

    const TIN* xb = xin + (size_t)n * node_stride + (size_t)t0 * t_stride;
    float acc[4] = {0.f, 0.f, 0.f, 0.f};

#pragma unroll 2
    for (int k4 = 0; k4 < 16; ++k4) {
        float4 xv[4];
#pragma unroll
        for (int r = 0; r < 4; ++r)
            xv[r] = ld4(xb + (size_t)r * t_stride + k4 * 4);
        float w0 = Ws[(4 * k4 + 0) * 64 + c];
        float w1 = Ws[(4 * k4 + 1) * 64 + c];
        float w2 = Ws[(4 * k4 + 2) * 64 + c];
        float w3 = Ws[(4 * k4 + 3) * 64 + c];
#pragma unroll
        for (int r = 0; r < 4; ++r) {
            acc[r] = fmaf(xv[r].x, w0, acc[r]);
            acc[r] = fmaf(xv[r].y, w1, acc[r]);
            acc[r] = fmaf(xv[r].z, w2, acc[r]);
            acc[r] = fmaf(xv[r].w, w3, acc[r]);
        }
    }

    float as_w = att_s[c];
    float ad_w = att_d[c];
    bf16*  hn  = hout + (size_t)n * 512;
    unsigned short* asn = asrc + (size_t)n * (H * 8);
    float* adn = adst + (size_t)n * (H * 8);
#pragma unroll
    for (int r = 0; r < 4; ++r) {
        int tt = t0 + r;
        float a = acc[r];
        hn[tt * 64 + c] = __float2bfloat16(a);
        float vs = a * as_w;
        float vd = a * ad_w;
#pragma unroll
        for (int off = 1; off < C; off <<= 1) {
            vs += __shfl_xor(vs, off, 64);
            vd += __shfl_xor(vd, off, 64);
        }
        if ((c % C) == 0) {
            int hd = c / C;
            asn[hd * 8 + tt] = f2bfu(vs);
            adn[hd * 8 + tt] = vd;
        }
    }
}

// ---- Edge-softmax aggregation, TB=8 single sweep ---------------------------
// grid (BPT): one wave per dst node, all 8 timesteps at once.
//   H=8: alpha at lanes (edge l&7, head l>>3): 16B bf16x8 load = all 8 t;
//        p[t] broadcast via static ds_swizzle (lane' = (lane&0x18)|Q).
//   H=1: lane = edge; alpha 16B bf16x8 = all 8 t; p via SGPR readlane.
//   h gather: 8 scalar 2B loads off one uniform row base per edge.

#define SWZ(PF, Q) __uint_as_float(__builtin_amdgcn_ds_swizzle(__float_as_uint(PF), ((Q) << 5) | 0x18))

template <int H, bool FINAL>
__global__ __launch_bounds__(256) void gat_edge_kernel(
    const bf16* __restrict__ h_all,      // [N][8*64] bf16 (t-inner)
    const unsigned short* __restrict__ asrc_all, // [N][H][8] bf16
    const float* __restrict__ adst_all,  // [N][H][8] f32
    const int* __restrict__ row,         // [N+1]
    const int* __restrict__ esrc,        // [Etot]
    const float* __restrict__ bias,      // [64]
    bf16* __restrict__ outb,             // (!FINAL) [N][8*64] bf16
    float* __restrict__ outf,            // (FINAL)  [T][N*64] f32
    int N) {
    int tid  = threadIdx.x;
    int lane = tid & 63;
    int n    = blockIdx.x * 4 + (tid >> 6);
    if (n >= N) return;

    const char* asrcb = (const char*)asrc_all;
    const unsigned short* hb = (const unsigned short*)h_all;
    const int head = (H == 8) ? (lane >> 3) : 0;

    float adn[8];
    {
        const float* adp = adst_all + (size_t)n * (H * 8) + head * 8;
        float4 d0 = ld4(adp), d1 = ld4(adp + 4);
        adn[0] = d0.x; adn[1] = d0.y; adn[2] = d0.z; adn[3] = d0.w;
        adn[4] = d1.x; adn[5] = d1.y; adn[6] = d1.z; adn[7] = d1.w;
    }

    int e0  = row[n];
    int deg = row[n + 1] - e0;

    float lsum[8] = {0.f, 0.f, 0.f, 0.f, 0.f, 0.f, 0.f, 0.f};
    float acc[8]  = {0.f, 0.f, 0.f, 0.f, 0.f, 0.f, 0.f, 0.f};

    for (int base = 0; base < deg; base += 64) {
        int cnt = deg - base; if (cnt > 64) cnt = 64;
        int sv = (lane < cnt) ? esrc[e0 + base + lane] : 0;

        if constexpr (H == 8) {
            unsigned head16 = (unsigned)(head << 4);
            unsigned l7_4   = (unsigned)((lane & 7) << 2);
#pragma unroll
            for (int sub = 0; sub < 8; ++sub) {
                if (sub * 8 >= cnt) break;
                int svj = __builtin_amdgcn_ds_bpermute(sub * 32 + l7_4, sv);
                // alpha: 16B = 8 bf16 t-values for (src svj, head)
                int4 a16 = *(const int4*)(asrcb + ((((unsigned)svj) << 7) | head16));
                bool valid = (sub * 8 + (lane & 7) < cnt);
                float p[8];
                {
                    float at[8] = {lo16(a16.x), hi16(a16.x), lo16(a16.y), hi16(a16.y),
                                   lo16(a16.z), hi16(a16.z), lo16(a16.w), hi16(a16.w)};
#pragma unroll
                    for (int t = 0; t < 8; ++t) {
                        float tv = at[t] + adn[t];
                        tv = tv > 0.f ? tv : 0.2f * tv;  // leaky_relu(0.2)
                        tv = valid ? tv : -INFINITY;
                        p[t] = __expf(tv);               // padded -> 0
                        lsum[t] += p[t];
                    }
                }
#define ACC_EDGE(Q)                                                            \
    {                                                                          \
        unsigned sj = (unsigned)__builtin_amdgcn_readlane(sv, sub * 8 + (Q));  \
        const unsigned short* hrow = hb + ((size_t)sj << 9) + lane;            \
        acc[0] = fmaf(SWZ(p[0], Q), bf2f(hrow[0]),   acc[0]);                  \
        acc[1] = fmaf(SWZ(p[1], Q), bf2f(hrow[64]),  acc[1]);                  \
        acc[2] = fmaf(SWZ(p[2], Q), bf2f(hrow[128]), acc[2]);                  \
        acc[3] = fmaf(SWZ(p[3], Q), bf2f(hrow[192]), acc[3]);                  \
        acc[4] = fmaf(SWZ(p[4], Q), bf2f(hrow[256]), acc[4]);                  \
        acc[5] = fmaf(SWZ(p[5], Q), bf2f(hrow[320]), acc[5]);                  \
        acc[6] = fmaf(SWZ(p[6], Q), bf2f(hrow[384]), acc[6]);                  \
        acc[7] = fmaf(SWZ(p[7], Q), bf2f(hrow[448]), acc[7]);                  \
    }
                ACC_EDGE(0) ACC_EDGE(1) ACC_EDGE(2) ACC_EDGE(3)
                ACC_EDGE(4) ACC_EDGE(5) ACC_EDGE(6) ACC_EDGE(7)
#undef ACC_EDGE
            }
        } else {
            // H == 1: alpha at lane = edge; 16B bf16x8 = all 8 t
            int4 a16 = *(const int4*)(asrcb + (((unsigned)sv) << 4));
            float p[8];
            {
                float at[8] = {lo16(a16.x), hi16(a16.x), lo16(a16.y), hi16(a16.y),
                               lo16(a16.z), hi16(a16.z), lo16(a16.w), hi16(a16.w)};
#pragma unroll
                for (int t = 0; t < 8; ++t) {
                    float tv = at[t] + adn[t];
                    tv = tv > 0.f ? tv : 0.2f * tv;      // leaky_relu(0.2)
                    tv = (lane < cnt) ? tv : -INFINITY;
                    p[t] = __expf(tv);                   // padded -> 0
                    lsum[t] += p[t];
                }
            }
            for (int j0 = 0; j0 < cnt; j0 += 8) {
#pragma unroll
                for (int q = 0; q < 8; ++q) {
                    int j = j0 + q;                      // j>=cnt: p==0, safe
                    unsigned sj = (unsigned)__builtin_amdgcn_readlane(sv, j);
                    const unsigned short* hrow = hb + ((size_t)sj << 9) + lane;
#define PJ(T) __uint_as_float(__builtin_amdgcn_readlane(__float_as_uint(p[T]), j))
                    acc[0] = fmaf(PJ(0), bf2f(hrow[0]),   acc[0]);
                    acc[1] = fmaf(PJ(1), bf2f(hrow[64]),  acc[1]);
                    acc[2] = fmaf(PJ(2), bf2f(hrow[128]), acc[2]);
                    acc[3] = fmaf(PJ(3), bf2f(hrow[192]), acc[3]);
                    acc[4] = fmaf(PJ(4), bf2f(hrow[256]), acc[4]);
                    acc[5] = fmaf(PJ(5), bf2f(hrow[320]), acc[5]);
                    acc[6] = fmaf(PJ(6), bf2f(hrow[384]), acc[6]);
                    acc[7] = fmaf(PJ(7), bf2f(hrow[448]), acc[7]);
#undef PJ
                }
            }
        }
    }

    float bi = bias[lane];
#pragma unroll
    for (int t = 0; t < 8; ++t) {
        float ls = lsum[t];
        if constexpr (H == 8) {
            ls += __shfl_xor(ls, 1, 64);
            ls += __shfl_xor(ls, 2, 64);
            ls += __shfl_xor(ls, 4, 64);
        } else {
#pragma unroll
            for (int o = 1; o < 64; o <<= 1) ls += __shfl_xor(ls, o, 64);
        }
        float v = acc[t] / (ls + 1e-16f) + bi;
        if (!FINAL) {
            float y = v > 0.f ? v : expm1f(v);           // ELU
            outb[(size_t)n * 512 + t * 64 + lane] = __float2bfloat16(y);
        } else {
            float mx = v;
#pragma unroll
            for (int off = 1; off < 64; off <<= 1) mx = fmaxf(mx, __shfl_xor(mx, off, 64));
            float ex = __expf(v - mx);
            float sm = ex;
#pragma unroll
            for (int off = 1; off < 64; off <<= 1) sm += __shfl_xor(sm, off, 64);
            outf[(size_t)t * N * 64 + (size_t)n * 64 + lane] =
                (v - mx) - __logf(sm);
        }
    }
}

// ---------------------------------------------------------------------------

extern "C" void kernel_launch(void* const* d_in, const int* in_sizes, int n_in,
                              void* d_out, int out_size, void* d_ws, size_t ws_size,
                              hipStream_t stream) {
    const float* x        = (const float*)d_in[0];   // [T,N,64]
    const int*   eidx     = (const int*)d_in[1];     // [2,E]
    const float* W1       = (const float*)d_in[2];
    const float* att_src1 = (const float*)d_in[3];
    const float* att_dst1 = (const float*)d_in[4];
    const float* bias1    = (const float*)d_in[5];
    const float* W2       = (const float*)d_in[6];
    const float* att_src2 = (const float*)d_in[7];
    const float* att_dst2 = (const float*)d_in[8];
    const float* bias2    = (const float*)d_in[9];
    float* dout = (float*)d_out;

    const int N = 50000;
    const int F = 64;
    const int E = in_sizes[1] / 2;
    const int T = in_sizes[0] / (N * F);   // == 8 (layouts hardcode T=8)
    const int NT = T * N;
    const int Etot = E + N;
    const int BPT = (N + 3) / 4;
    const int M  = N * TILES;
    const int SB = (M + 255) / 256;

    const int* srcs = eidx;
    const int* dsts = eidx + E;

    char* ws = (char*)d_ws;
    size_t off = 0;
    auto carve = [&](size_t bytes) -> void* {
        void* p = ws + off;
        off = (off + bytes + 255) & ~(size_t)255;
        return p;
    };
    bf16*  h_all  = (bf16*)carve((size_t)NT * 64 * sizeof(bf16));   // [N][8*64]
    bf16*  y1_all = (bf16*)carve((size_t)NT * 64 * sizeof(bf16));   // [N][8*64]
    unsigned short* asrc = (unsigned short*)carve((size_t)NT * 8 * sizeof(unsigned short));
    float* adst   = (float*)carve((size_t)NT * 8 * sizeof(float));  // [N][H][8]
    int*   rowp   = (int*)carve((size_t)(N + 1) * sizeof(int));
    int*   cnt2   = (int*)carve((size_t)M * sizeof(int));
    int*   cur2   = (int*)carve((size_t)M * sizeof(int));
    int*   bsum   = (int*)carve((size_t)SB * sizeof(int));
    int*   boff   = (int*)carve((size_t)SB * sizeof(int));
    int*   esrc   = (int*)carve((size_t)Etot * sizeof(int));
    (void)ws_size;  // ~136 MB, fits

    // --- src-tiled CSR (graph identical across timesteps) ---
    hipMemsetAsync(cnt2, 0, (size_t)M * sizeof(int), stream);
    count2_kernel<<<(E + 255) / 256, 256, 0, stream>>>(srcs, dsts, cnt2, E);
    scanA_kernel<<<SB, 256, 0, stream>>>(cnt2, bsum, M);
    scanB_kernel<<<1, 1024, 0, stream>>>(bsum, boff, SB);
    scanC_kernel<<<SB, 256, 0, stream>>>(cnt2, boff, cur2, rowp, M, N);
    fill2_kernel<<<(E + N + 255) / 256, 256, 0, stream>>>(srcs, dsts, cur2, esrc, E, N);

    dim3 ggrid((N + 3) / 4, 2);
    // layer 1: x rows are [t][n][64] -> node_stride=64, t_stride=N*64
    gemm_att_kernel<float, 8, 8><<<ggrid, 256, 0, stream>>>(
        x, 64, (size_t)N * 64, W1, att_src1, att_dst1, h_all, asrc, adst, N);
    gat_edge_kernel<8, false><<<BPT, 256, 0, stream>>>(
        h_all, asrc, adst, rowp, esrc, bias1, y1_all, nullptr, N);
    // layer 2: y1 rows are t-inner [n][8][64] -> node_stride=512, t_stride=64
    gemm_att_kernel<bf16, 1, 64><<<ggrid, 256, 0, stream>>>(
        y1_all, 512, 64, W2, att_src2, att_dst2, h_all, asrc, adst, N);
    gat_edge_kernel<1, true><<<BPT, 256, 0, stream>>>(
        h_all, asrc, adst, rowp, esrc, bias2, nullptr, dout, N);
}

// Round 25
// 1060.981 us; speedup vs baseline: 1.0533x; 1.0533x over previous
//
#include <hip/hip_runtime.h>
#include <hip/hip_bf16.h>
#include <math.h>

// ---------------------------------------------------------------------------
// GAT 2-layer network on MI355X.
// r22 = r20 (best known: TB=4 t-inner h, src-tiled parallel-scan CSR)
// + bf16 alpha tables in per-head t-contiguous layout:
//   asrc[n][h][8t] bf16 (8B int2 per (edge,head) alpha read, was 4x f32)
//   adst[n][h][8t] f32  (float4 prologue load)
// TB=8 rejected twice (r19: 92 VGPR, r21: 84 VGPR -> Occ ~27%); TB=4 at
// 48 VGPR / Occ 52% is the structural optimum. No online max. f32 accum.
// ---------------------------------------------------------------------------

typedef __hip_bfloat16 bf16;

#define TILES  16
#define TSHIFT 12   // tile = src >> 12  (4096 nodes/tile)

__device__ __forceinline__ float bf2f(unsigned short u) {
    return __uint_as_float(((unsigned int)u) << 16);
}
__device__ __forceinline__ float lo16(int u) {
    return __uint_as_float(((unsigned)u) << 16);
}
__device__ __forceinline__ float hi16(int u) {
    return __uint_as_float(((unsigned)u) & 0xFFFF0000u);
}
__device__ __forceinline__ unsigned short f2bfu(float f) {
    bf16 b = __float2bfloat16(f);
    return *reinterpret_cast<unsigned short*>(&b);
}

// ---- CSR construction (src-tiled, parallel scan) ---------------------------

__global__ __launch_bounds__(256) void count2_kernel(const int* __restrict__ srcs,
                                                     const int* __restrict__ dsts,
                                                     int* cnt2, int E) {
    int i = blockIdx.x * 256 + threadIdx.x;
    if (i < E) atomicAdd(&cnt2[dsts[i] * TILES + (srcs[i] >> TSHIFT)], 1);
}

__device__ __forceinline__ int bucket_val(const int* __restrict__ cnt2, int idx, int M) {
    if (idx >= M) return 0;
    int n = idx >> 4, tile = idx & (TILES - 1);
    return cnt2[idx] + ((tile == (n >> TSHIFT)) ? 1 : 0);   // self-loop folded in
}

__global__ __launch_bounds__(256) void scanA_kernel(const int* __restrict__ cnt2,
                                                    int* bsum, int M) {
    __shared__ int sd[256];
    int tid = threadIdx.x;
    int idx = blockIdx.x * 256 + tid;
    int v = bucket_val(cnt2, idx, M);
    sd[tid] = v;
    __syncthreads();
    for (int off = 128; off > 0; off >>= 1) {
        if (tid < off) sd[tid] += sd[tid + off];
        __syncthreads();
    }
    if (tid == 0) bsum[blockIdx.x] = sd[0];
}

__global__ __launch_bounds__(1024) void scanB_kernel(const int* __restrict__ bsum,
                                                     int* boff, int B) {
    __shared__ int ls[1024];
    int t = threadIdx.x;
    int chunk = (B + 1023) / 1024;
    int b = t * chunk;
    int sum = 0;
    for (int i = 0; i < chunk; ++i) {
        int idx = b + i;
        if (idx < B) sum += bsum[idx];
    }
    ls[t] = sum;
    __syncthreads();
    for (int off = 1; off < 1024; off <<= 1) {
        int v = (t >= off) ? ls[t - off] : 0;
        __syncthreads();
        ls[t] += v;
        __syncthreads();
    }
    int run = (t == 0) ? 0 : ls[t - 1];
    for (int i = 0; i < chunk; ++i) {
        int idx = b + i;
        if (idx < B) {
            boff[idx] = run;
            run += bsum[idx];
        }
    }
}

__global__ __launch_bounds__(256) void scanC_kernel(const int* __restrict__ cnt2,
                                                    const int* __restrict__ boff,
                                                    int* cur2, int* rowp, int M, int N) {
    __shared__ int sd[256];
    int tid = threadIdx.x;
    int idx = blockIdx.x * 256 + tid;
    int v = bucket_val(cnt2, idx, M);
    sd[tid] = v;
    __syncthreads();
    for (int off = 1; off < 256; off <<= 1) {
        int t = (tid >= off) ? sd[tid - off] : 0;
        __syncthreads();
        sd[tid] += t;
        __syncthreads();
    }
    int inc = sd[tid];
    int go  = boff[blockIdx.x] + inc - v;
    if (idx < M) {
        cur2[idx] = go;
        if ((idx & (TILES - 1)) == 0) rowp[idx >> 4] = go;
        if (idx == M - 1) rowp[N] = go + v;
    }
}

__global__ __launch_bounds__(256) void fill2_kernel(const int* __restrict__ srcs,
                                                    const int* __restrict__ dsts,
                                                    int* cur2, int* esrc, int E, int N) {
    int i = blockIdx.x * 256 + threadIdx.x;
    if (i >= E + N) return;
    int s, d;
    if (i < E) { s = srcs[i]; d = dsts[i]; }
    else       { s = i - E;   d = s; }      // self-loops
    int pos = atomicAdd(&cur2[d * TILES + (s >> TSHIFT)], 1);
    esrc[pos] = s;
}

// ---- vector loaders --------------------------------------------------------

__device__ __forceinline__ float4 ld4(const float* p) { return *(const float4*)p; }
__device__ __forceinline__ float4 ld4(const bf16* p) {
    ushort4 u = *(const ushort4*)p;
    float4 r;
    r.x = bf2f(u.x); r.y = bf2f(u.y); r.z = bf2f(u.z); r.w = bf2f(u.w);
    return r;
}

// ---- GEMM (h = x@W) fused with attention dot-products, t-batched rows ------
// grid (N/4, 2): wave = node n, rows = timesteps t0..t0+3.
// Outputs: h[n][8t][64c] bf16; asrc[n][H][8t] bf16; adst[n][H][8t] f32.

template <typename TIN, int H, int C>
__global__ __launch_bounds__(256) void gemm_att_kernel(
    const TIN* __restrict__ xin,
    size_t node_stride, size_t t_stride,
    const float* __restrict__ Wm,    // [64,64]
    const float* __restrict__ att_s, // [H*C]
    const float* __restrict__ att_d, // [H*C]
    bf16* __restrict__ hout,         // [N][8*64] bf16 (t-inner)
    unsigned short* __restrict__ asrc, // [N][H][8] bf16
    float* __restrict__ adst,        // [N][H][8] f32
    int N) {
    __shared__ float Ws[64 * 64];
    int tid = threadIdx.x;
    {
        const float4* W4 = (const float4*)Wm;
        float4* Ws4 = (float4*)Ws;
#pragma unroll
        for (int i = 0; i < 4; ++i) Ws4[tid + 256 * i] = W4[tid + 256 * i];
    }
    __syncthreads();

    int c  = tid & 63;
    int wv = tid >> 6;
    int t0 = blockIdx.y * 4;
    int n  = blockIdx.x * 4 + wv;
    if (n >= N) return;

    const TIN* xb = xin + (size_t)n * node_stride + (size_t)t0 * t_stride;
    float acc[4] = {0.f, 0.f, 0.f, 0.f};

#pragma unroll 2
    for (int k4 = 0; k4 < 16; ++k4) {
        float4 xv[4];
#pragma unroll
        for (int r = 0; r < 4; ++r)
            xv[r] = ld4(xb + (size_t)r * t_stride + k4 * 4);
        float w0 = Ws[(4 * k4 + 0) * 64 + c];
        float w1 = Ws[(4 * k4 + 1) * 64 + c];
        float w2 = Ws[(4 * k4 + 2) * 64 + c];
        float w3 = Ws[(4 * k4 + 3) * 64 + c];
#pragma unroll
        for (int r = 0; r < 4; ++r) {
            acc[r] = fmaf(xv[r].x, w0, acc[r]);
            acc[r] = fmaf(xv[r].y, w1, acc[r]);
            acc[r] = fmaf(xv[r].z, w2, acc[r]);
            acc[r] = fmaf(xv[r].w, w3, acc[r]);
        }
    }

    float as_w = att_s[c];
    float ad_w = att_d[c];
    bf16*  hn  = hout + (size_t)n * 512;
    unsigned short* asn = asrc + (size_t)n * (H * 8);
    float* adn = adst + (size_t)n * (H * 8);
#pragma unroll
    for (int r = 0; r < 4; ++r) {
        int tt = t0 + r;
        float a = acc[r];
        hn[tt * 64 + c] = __float2bfloat16(a);
        float vs = a * as_w;
        float vd = a * ad_w;
#pragma unroll
        for (int off = 1; off < C; off <<= 1) {
            vs += __shfl_xor(vs, off, 64);
            vd += __shfl_xor(vd, off, 64);
        }
        if ((c % C) == 0) {
            int hd = c / C;
            asn[hd * 8 + tt] = f2bfu(vs);
            adn[hd * 8 + tt] = vd;
        }
    }
}

// ---- Edge-softmax aggregation, TB=4 timesteps per wave ---------------------
// grid (BPT, T/4): t0 = 4*blockIdx.y. One wave per dst node.
//   H=8: alpha at lanes (edge l&7, head l>>3): 8B int2 = 4 bf16 t-values;
//        p broadcast via static ds_swizzle (lane' = (lane&0x18)|Q).
//   H=1: lane = edge; alpha 8B int2; p via SGPR readlane.
//   h-row base uniform (SGPR) via readlane; 4 t-gathers = 4 consecutive
//   lines of the node's contiguous 1KB block.

#define SWZ(PF, Q) __uint_as_float(__builtin_amdgcn_ds_swizzle(__float_as_uint(PF), ((Q) << 5) | 0x18))

template <int H, bool FINAL>
__global__ __launch_bounds__(256) void gat_edge_kernel(
    const bf16* __restrict__ h_all,      // [N][8*64] bf16 (t-inner)
    const unsigned short* __restrict__ asrc_all, // [N][H][8] bf16
    const float* __restrict__ adst_all,  // [N][H][8] f32
    const int* __restrict__ row,         // [N+1]
    const int* __restrict__ esrc,        // [Etot]
    const float* __restrict__ bias,      // [64]
    bf16* __restrict__ outb,             // (!FINAL) [N][8*64] bf16
    float* __restrict__ outf,            // (FINAL)  [T][N*64] f32
    int N) {
    int tid  = threadIdx.x;
    int lane = tid & 63;
    int t0   = blockIdx.y * 4;
    int n    = blockIdx.x * 4 + (tid >> 6);
    if (n >= N) return;

    const char* asrcb = (const char*)asrc_all;
    const unsigned short* hb = (const unsigned short*)h_all;

    const int head = (H == 8) ? (lane >> 3) : 0;
    float adn[4];
    {
        float4 d = ld4(adst_all + (size_t)n * (H * 8) + head * 8 + t0);
        adn[0] = d.x; adn[1] = d.y; adn[2] = d.z; adn[3] = d.w;
    }

    int e0  = row[n];
    int deg = row[n + 1] - e0;
    int toff = t0 * 64 + lane;

    float lsum[4] = {0.f, 0.f, 0.f, 0.f};
    float acc[4]  = {0.f, 0.f, 0.f, 0.f};

    for (int base = 0; base < deg; base += 64) {
        int cnt = deg - base; if (cnt > 64) cnt = 64;
        int sv = (lane < cnt) ? esrc[e0 + base + lane] : 0;

        if constexpr (H == 8) {
            unsigned hoff = (unsigned)((head << 4) + (t0 << 1));
            unsigned l7_4 = (unsigned)((lane & 7) << 2);
#pragma unroll
            for (int sub = 0; sub < 8; ++sub) {
                if (sub * 8 >= cnt) break;
                int svj = __builtin_amdgcn_ds_bpermute(sub * 32 + l7_4, sv);
                // alpha: 8B = 4 bf16 t-values for (src svj, head)
                int2 a8 = *(const int2*)(asrcb + ((((unsigned)svj) << 7) + hoff));
                bool valid = (sub * 8 + (lane & 7) < cnt);
                float p[4];
                {
                    float at[4] = {lo16(a8.x), hi16(a8.x), lo16(a8.y), hi16(a8.y)};
#pragma unroll
                    for (int i = 0; i < 4; ++i) {
                        float tv = at[i] + adn[i];
                        tv = tv > 0.f ? tv : 0.2f * tv;  // leaky_relu(0.2)
                        tv = valid ? tv : -INFINITY;
                        p[i] = __expf(tv);               // padded -> 0
                        lsum[i] += p[i];
                    }
                }
#define ACC_EDGE(Q)                                                            \
    {                                                                          \
        unsigned sj = (unsigned)__builtin_amdgcn_readlane(sv, sub * 8 + (Q));  \
        const unsigned short* hrow = hb + ((size_t)sj << 9) + toff;            \
        acc[0] = fmaf(SWZ(p[0], Q), bf2f(hrow[0]),   acc[0]);                  \
        acc[1] = fmaf(SWZ(p[1], Q), bf2f(hrow[64]),  acc[1]);                  \
        acc[2] = fmaf(SWZ(p[2], Q), bf2f(hrow[128]), acc[2]);                  \
        acc[3] = fmaf(SWZ(p[3], Q), bf2f(hrow[192]), acc[3]);                  \
    }
                ACC_EDGE(0) ACC_EDGE(1) ACC_EDGE(2) ACC_EDGE(3)
                ACC_EDGE(4) ACC_EDGE(5) ACC_EDGE(6) ACC_EDGE(7)
#undef ACC_EDGE
            }
        } else {
            // H == 1: alpha at lane = edge; 8B = 4 bf16 t-values
            int2 a8 = *(const int2*)(asrcb + ((((unsigned)sv) << 4) + (t0 << 1)));
            float p[4];
            {
                float at[4] = {lo16(a8.x), hi16(a8.x), lo16(a8.y), hi16(a8.y)};
#pragma unroll
                for (int i = 0; i < 4; ++i) {
                    float tv = at[i] + adn[i];
                    tv = tv > 0.f ? tv : 0.2f * tv;      // leaky_relu(0.2)
                    tv = (lane < cnt) ? tv : -INFINITY;
                    p[i] = __expf(tv);                   // padded -> 0
                    lsum[i] += p[i];
                }
            }
            for (int j0 = 0; j0 < cnt; j0 += 8) {
#pragma unroll
                for (int q = 0; q < 8; ++q) {
                    int j = j0 + q;                      // j>=cnt: p==0, safe
                    unsigned sj = (unsigned)__builtin_amdgcn_readlane(sv, j);
                    const unsigned short* hrow = hb + ((size_t)sj << 9) + toff;
#define PJ(T) __uint_as_float(__builtin_amdgcn_readlane(__float_as_uint(p[T]), j))
                    acc[0] = fmaf(PJ(0), bf2f(hrow[0]),   acc[0]);
                    acc[1] = fmaf(PJ(1), bf2f(hrow[64]),  acc[1]);
                    acc[2] = fmaf(PJ(2), bf2f(hrow[128]), acc[2]);
                    acc[3] = fmaf(PJ(3), bf2f(hrow[192]), acc[3]);
#undef PJ
                }
            }
        }
    }

#pragma unroll
    for (int i = 0; i < 4; ++i) {
        float ls = lsum[i];
        if constexpr (H == 8) {
            ls += __shfl_xor(ls, 1, 64);
            ls += __shfl_xor(ls, 2, 64);
            ls += __shfl_xor(ls, 4, 64);
        } else {
#pragma unroll
            for (int o = 1; o < 64; o <<= 1) ls += __shfl_xor(ls, o, 64);
        }
        float v = acc[i] / (ls + 1e-16f) + bias[lane];
        if (!FINAL) {
            float y = v > 0.f ? v : expm1f(v);           // ELU
            outb[(size_t)n * 512 + (t0 + i) * 64 + lane] = __float2bfloat16(y);
        } else {
            float mx = v;
#pragma unroll
            for (int off = 1; off < 64; off <<= 1) mx = fmaxf(mx, __shfl_xor(mx, off, 64));
            float ex = __expf(v - mx);
            float sm = ex;
#pragma unroll
            for (int off = 1; off < 64; off <<= 1) sm += __shfl_xor(sm, off, 64);
            outf[(size_t)(t0 + i) * N * 64 + (size_t)n * 64 + lane] =
                (v - mx) - __logf(sm);
        }
    }
}

// ---------------------------------------------------------------------------

extern "C" void kernel_launch(void* const* d_in, const int* in_sizes, int n_in,
                              void* d_out, int out_size, void* d_ws, size_t ws_size,
                              hipStream_t stream) {
    const float* x        = (const float*)d_in[0];   // [T,N,64]
    const int*   eidx     = (const int*)d_in[1];     // [2,E]
    const float* W1       = (const float*)d_in[2];
    const float* att_src1 = (const float*)d_in[3];
    const float* att_dst1 = (const float*)d_in[4];
    const float* bias1    = (const float*)d_in[5];
    const float* W2       = (const float*)d_in[6];
    const float* att_src2 = (const float*)d_in[7];
    const float* att_dst2 = (const float*)d_in[8];
    const float* bias2    = (const float*)d_in[9];
    float* dout = (float*)d_out;

    const int N = 50000;
    const int F = 64;
    const int E = in_sizes[1] / 2;
    const int T = in_sizes[0] / (N * F);   // == 8 (layouts hardcode T=8)
    const int NT = T * N;
    const int Etot = E + N;
    const int BPT = (N + 3) / 4;
    const int M  = N * TILES;
    const int SB = (M + 255) / 256;

    const int* srcs = eidx;
    const int* dsts = eidx + E;

    char* ws = (char*)d_ws;
    size_t off = 0;
    auto carve = [&](size_t bytes) -> void* {
        void* p = ws + off;
        off = (off + bytes + 255) & ~(size_t)255;
        return p;
    };
    bf16*  h_all  = (bf16*)carve((size_t)NT * 64 * sizeof(bf16));   // [N][8*64]
    bf16*  y1_all = (bf16*)carve((size_t)NT * 64 * sizeof(bf16));   // [N][8*64]
    unsigned short* asrc = (unsigned short*)carve((size_t)NT * 8 * sizeof(unsigned short));
    float* adst   = (float*)carve((size_t)NT * 8 * sizeof(float));  // [N][H][8]
    int*   rowp   = (int*)carve((size_t)(N + 1) * sizeof(int));
    int*   cnt2   = (int*)carve((size_t)M * sizeof(int));
    int*   cur2   = (int*)carve((size_t)M * sizeof(int));
    int*   bsum   = (int*)carve((size_t)SB * sizeof(int));
    int*   boff   = (int*)carve((size_t)SB * sizeof(int));
    int*   esrc   = (int*)carve((size_t)Etot * sizeof(int));
    (void)ws_size;  // ~136 MB, fits

    // --- src-tiled CSR (graph identical across timesteps) ---
    hipMemsetAsync(cnt2, 0, (size_t)M * sizeof(int), stream);
    count2_kernel<<<(E + 255) / 256, 256, 0, stream>>>(srcs, dsts, cnt2, E);
    scanA_kernel<<<SB, 256, 0, stream>>>(cnt2, bsum, M);
    scanB_kernel<<<1, 1024, 0, stream>>>(bsum, boff, SB);
    scanC_kernel<<<SB, 256, 0, stream>>>(cnt2, boff, cur2, rowp, M, N);
    fill2_kernel<<<(E + N + 255) / 256, 256, 0, stream>>>(srcs, dsts, cur2, esrc, E, N);

    dim3 ggrid((N + 3) / 4, 2);
    dim3 egrid(BPT, T / 4);
    // layer 1: x rows are [t][n][64] -> node_stride=64, t_stride=N*64
    gemm_att_kernel<float, 8, 8><<<ggrid, 256, 0, stream>>>(
        x, 64, (size_t)N * 64, W1, att_src1, att_dst1, h_all, asrc, adst, N);
    gat_edge_kernel<8, false><<<egrid, 256, 0, stream>>>(
        h_all, asrc, adst, rowp, esrc, bias1, y1_all, nullptr, N);
    // layer 2: y1 rows are t-inner [n][8][64] -> node_stride=512, t_stride=64
    gemm_att_kernel<bf16, 1, 64><<<ggrid, 256, 0, stream>>>(
        y1_all, 512, 64, W2, att_src2, att_dst2, h_all, asrc, adst, N);
    gat_edge_kernel<1, true><<<egrid, 256, 0, stream>>>(
        h_all, asrc, adst, rowp, esrc, bias2, nullptr, dout, N);
}